// Round 5
// baseline (246.203 us; speedup 1.0000x reference)
//
#include <hip/hip_runtime.h>

#define N_NODES 50000
#define N_EDGES 800000
#define IN_CH 256
#define HID_CH 128
#define OUT_CH 64
#define CAP 64   // bucket slots/node (ushort); deg~Poisson(16), P(deg>=64) ~ 1e-18

typedef _Float16 f16;
typedef _Float16 f16x8 __attribute__((ext_vector_type(8)));
typedef _Float16 f16x2 __attribute__((ext_vector_type(2)));
typedef float f32x4 __attribute__((ext_vector_type(4)));
typedef unsigned short u16;

// ---------------- CSR bucket fill (device body, fused below) ----------------
__device__ __forceinline__ void fill_body(int bid, const int* __restrict__ src,
                                          const int* __restrict__ dst,
                                          int* __restrict__ cnt,
                                          u16* __restrict__ bucket, int E) {
    int e = bid * 256 + threadIdx.x;
    if (e < E) {
        int d = dst[e];
        int pos = atomicAdd(&cnt[d], 1);
        if (pos < CAP) bucket[d * CAP + pos] = (u16)src[e];
    }
}

__global__ __launch_bounds__(256) void k_dis(const int* __restrict__ cnt,
                                             float* __restrict__ dis, int N) {
    int i = blockIdx.x * 256 + threadIdx.x;
    if (i < N) dis[i] = rsqrtf((float)cnt[i] + 1.0f);
}

// ---------------- W -> MFMA B-fragment swizzle (one-time, tiny) ----------------
template <int K, int N>
__global__ __launch_bounds__(256) void k_swizzleB(const float* __restrict__ W,
                                                  f16* __restrict__ Bsw) {
    constexpr int NTILES = N / 16;
    int idx = blockIdx.x * 256 + threadIdx.x;
    if (idx >= K * N) return;
    int j = idx & 7;
    int lane = (idx >> 3) & 63;
    int rest = idx >> 9;            // ks*NTILES + nt
    int nt = rest % NTILES;
    int ks = rest / NTILES;
    int k = ks * 32 + (lane >> 4) * 8 + j;
    int n = nt * 16 + (lane & 15);
    Bsw[idx] = (f16)W[(size_t)k * N + n];
}

// ---------------- MFMA fp16 GEMM body: C = [dis[m]*] (A@B) ----------------
// 4 waves/block, wave computes 16 rows x N. No LDS/barriers; B pre-swizzled (L2).
template <int K, int N, bool A_FP32, bool RELU, bool SCALE>
__device__ __forceinline__ void gemm_body(int bid, const void* __restrict__ Av,
                                          const f16* __restrict__ Bsw,
                                          const float* __restrict__ dis,
                                          f16* __restrict__ C, int M) {
    constexpr int KSTEPS = K / 32, NTILES = N / 16;
    const int tid = threadIdx.x;
    const int wave = tid >> 6, lane = tid & 63;
    const int quad = lane >> 4, l16 = lane & 15;
    int row = bid * 64 + wave * 16 + l16;
    const int rowc = row < M ? row : M - 1;   // clamp; OOB rows discarded on store

    f32x4 acc[NTILES];
#pragma unroll
    for (int t = 0; t < NTILES; ++t) acc[t] = (f32x4){0.f, 0.f, 0.f, 0.f};

#pragma unroll
    for (int ks = 0; ks < KSTEPS; ++ks) {
        f16x8 afrag;
        if (A_FP32) {
            const float* A = (const float*)Av;
            const float4* p = (const float4*)(A + (size_t)rowc * K + ks * 32 + quad * 8);
            float4 v0 = p[0], v1 = p[1];
            afrag[0] = (f16)v0.x; afrag[1] = (f16)v0.y;
            afrag[2] = (f16)v0.z; afrag[3] = (f16)v0.w;
            afrag[4] = (f16)v1.x; afrag[5] = (f16)v1.y;
            afrag[6] = (f16)v1.z; afrag[7] = (f16)v1.w;
        } else {
            const f16* A = (const f16*)Av;
            afrag = *(const f16x8*)(A + (size_t)rowc * K + ks * 32 + quad * 8);
            if (RELU) {
#pragma unroll
                for (int j = 0; j < 8; ++j)
                    afrag[j] = afrag[j] > (f16)0 ? afrag[j] : (f16)0;
            }
        }
#pragma unroll
        for (int t = 0; t < NTILES; ++t) {
            f16x8 bfrag = *(const f16x8*)(Bsw + (((size_t)ks * NTILES + t) * 64 + lane) * 8);
            acc[t] = __builtin_amdgcn_mfma_f32_16x16x32_f16(afrag, bfrag, acc[t], 0, 0, 0);
        }
    }

    // C/D layout: col = lane&15, row = quad*4 + reg
    int rbase = bid * 64 + wave * 16 + quad * 4;
#pragma unroll
    for (int r = 0; r < 4; ++r) {
        int gr = rbase + r;
        if (gr < M) {
            float d = SCALE ? dis[gr] : 1.0f;
#pragma unroll
            for (int t = 0; t < NTILES; ++t)
                C[(size_t)gr * N + t * 16 + l16] = (f16)(SCALE ? acc[t][r] * d : acc[t][r]);
        }
    }
}

// Fused: fill blocks first (memory-bound), then gemm1 blocks (MFMA-bound).
__global__ __launch_bounds__(256) void k_fill_gemm1(const int* __restrict__ src,
                                                    const int* __restrict__ dst,
                                                    int* __restrict__ cnt,
                                                    u16* __restrict__ bucket, int E,
                                                    int fillBlocks,
                                                    const float* __restrict__ x,
                                                    const f16* __restrict__ Bsw,
                                                    f16* __restrict__ h1, int M) {
    if ((int)blockIdx.x < fillBlocks) {
        fill_body(blockIdx.x, src, dst, cnt, bucket, E);
        return;
    }
    gemm_body<IN_CH, HID_CH, true, false, false>(blockIdx.x - fillBlocks, x, Bsw,
                                                 nullptr, h1, M);
}

template <int K, int N, bool A_FP32, bool RELU, bool SCALE>
__global__ __launch_bounds__(256) void k_gemm(const void* __restrict__ Av,
                                              const f16* __restrict__ Bsw,
                                              const float* __restrict__ dis,
                                              f16* __restrict__ C, int M) {
    gemm_body<K, N, A_FP32, RELU, SCALE>(blockIdx.x, Av, Bsw, dis, C, M);
}

// ---------------- pull aggregation ----------------
// EDGE_SCALE: h unscaled -> acc += dis[s]*h[s]; else h pre-scaled -> acc += g[s].
// out[u] = du*( du*h[u] | g[u] + sum ) + bias ; fp16 store or fused-ReLU fp32 store.
template <int C, bool EDGE_SCALE, bool RELU_OUT_F32>
__global__ __launch_bounds__(256) void k_pull(const f16* __restrict__ g,
                                              const float* __restrict__ dis,
                                              const float* __restrict__ bias,
                                              const int* __restrict__ cnt,
                                              const u16* __restrict__ bucket,
                                              void* __restrict__ outv, int N) {
    constexpr int LPN = C / 2;
    int tid = blockIdx.x * 256 + threadIdx.x;
    int u = tid / LPN;
    int sub = tid % LPN;
    if (u >= N) return;

    float du = dis[u];
    f16x2 hv = *(const f16x2*)(g + (size_t)u * C + sub * 2);
    float a0 = EDGE_SCALE ? du * (float)hv[0] : (float)hv[0];
    float a1 = EDGE_SCALE ? du * (float)hv[1] : (float)hv[1];

    int n = cnt[u];
    if (n > CAP) n = CAP;
    const u16* row = bucket + u * CAP;   // 128B-aligned rows

    int k = 0;
    for (; k + 4 <= n; k += 4) {
        ushort4 s4 = *(const ushort4*)(row + k);   // one 8B index load
        f16x2 v0 = *(const f16x2*)(g + (size_t)s4.x * C + sub * 2);
        f16x2 v1 = *(const f16x2*)(g + (size_t)s4.y * C + sub * 2);
        f16x2 v2 = *(const f16x2*)(g + (size_t)s4.z * C + sub * 2);
        f16x2 v3 = *(const f16x2*)(g + (size_t)s4.w * C + sub * 2);
        if (EDGE_SCALE) {
            float d0 = dis[s4.x], d1 = dis[s4.y], d2 = dis[s4.z], d3 = dis[s4.w];
            a0 = fmaf(d0, (float)v0[0], a0); a1 = fmaf(d0, (float)v0[1], a1);
            a0 = fmaf(d1, (float)v1[0], a0); a1 = fmaf(d1, (float)v1[1], a1);
            a0 = fmaf(d2, (float)v2[0], a0); a1 = fmaf(d2, (float)v2[1], a1);
            a0 = fmaf(d3, (float)v3[0], a0); a1 = fmaf(d3, (float)v3[1], a1);
        } else {
            a0 += (float)v0[0] + (float)v1[0] + (float)v2[0] + (float)v3[0];
            a1 += (float)v0[1] + (float)v1[1] + (float)v2[1] + (float)v3[1];
        }
    }
    for (; k < n; ++k) {
        int s = row[k];
        f16x2 v = *(const f16x2*)(g + (size_t)s * C + sub * 2);
        float d = EDGE_SCALE ? dis[s] : 1.0f;
        a0 = fmaf(d, (float)v[0], a0);
        a1 = fmaf(d, (float)v[1], a1);
    }

    float o0 = fmaf(du, a0, bias[sub * 2]);
    float o1 = fmaf(du, a1, bias[sub * 2 + 1]);
    if (RELU_OUT_F32) {
        float2* out = (float2*)outv;
        out[(size_t)u * LPN + sub] = make_float2(fmaxf(o0, 0.f), fmaxf(o1, 0.f));
    } else {
        f16x2 o;
        o[0] = (f16)o0; o[1] = (f16)o1;
        *(f16x2*)((f16*)outv + (size_t)u * C + sub * 2) = o;
    }
}

// ---------------- launch ----------------

extern "C" void kernel_launch(void* const* d_in, const int* in_sizes, int n_in,
                              void* d_out, int out_size, void* d_ws, size_t ws_size,
                              hipStream_t stream) {
    const float* x  = (const float*)d_in[0];
    const int* ei   = (const int*)d_in[1];
    const float* W1 = (const float*)d_in[2];
    const float* b1 = (const float*)d_in[3];
    const float* W2 = (const float*)d_in[4];
    const float* b2 = (const float*)d_in[5];
    float* out = (float*)d_out;

    const int* src = ei;
    const int* dst = ei + N_EDGES;

    char* ws = (char*)d_ws;
    size_t off = 0;
    auto alloc = [&](size_t bytes) -> void* {
        off = (off + 255) & ~(size_t)255;
        void* p = ws + off;
        off += bytes;
        return p;
    };
    int*   cnt    = (int*)alloc((size_t)N_NODES * 4);
    float* dis    = (float*)alloc((size_t)N_NODES * 4);
    u16*   bucket = (u16*)alloc((size_t)N_NODES * CAP * 2);        // 6.4 MB
    f16*   W1sw   = (f16*)alloc((size_t)IN_CH * HID_CH * 2);       // 64 KB
    f16*   W2sw   = (f16*)alloc((size_t)HID_CH * OUT_CH * 2);      // 16 KB
    f16*   h1     = (f16*)alloc((size_t)N_NODES * HID_CH * 2);     // 12.8 MB (unscaled)
    f16*   agg1   = (f16*)alloc((size_t)N_NODES * HID_CH * 2);     // 12.8 MB
    f16*   g2     = (f16*)alloc((size_t)N_NODES * OUT_CH * 2);     // 6.4 MB (prescaled)

    hipMemsetAsync(cnt, 0, (size_t)N_NODES * 4, stream);
    k_swizzleB<IN_CH, HID_CH><<<(IN_CH * HID_CH + 255) / 256, 256, 0, stream>>>(W1, W1sw);
    k_swizzleB<HID_CH, OUT_CH><<<(HID_CH * OUT_CH + 255) / 256, 256, 0, stream>>>(W2, W2sw);

    // fused: CSR fill (mem-bound) + layer-1 GEMM h1 = f16(x@W1) (MFMA-bound)
    const int fillBlocks = (N_EDGES + 255) / 256;
    const int gemm1Blocks = (N_NODES + 63) / 64;
    k_fill_gemm1<<<fillBlocks + gemm1Blocks, 256, 0, stream>>>(
        src, dst, cnt, bucket, N_EDGES, fillBlocks, x, W1sw, h1, N_NODES);

    k_dis<<<(N_NODES + 255) / 256, 256, 0, stream>>>(cnt, dis, N_NODES);

    // layer 1 agg: agg1 = f16( du*(du*h1[u] + sum dis[s]*h1[s]) + b1 )  (pre-ReLU)
    k_pull<HID_CH, true, false><<<(N_NODES * (HID_CH / 2) + 255) / 256, 256, 0, stream>>>(
        h1, dis, b1, cnt, bucket, agg1, N_NODES);

    // layer 2: g2 = dis*(relu(agg1) @ W2) ; out = relu( du*(g2[u]+sum g2[s]) + b2 )
    k_gemm<HID_CH, OUT_CH, false, true, true><<<(N_NODES + 63) / 64, 256, 0, stream>>>(
        agg1, W2sw, dis, g2, N_NODES);
    k_pull<OUT_CH, false, true><<<(N_NODES * (OUT_CH / 2) + 255) / 256, 256, 0, stream>>>(
        g2, dis, b2, cnt, bucket, out, N_NODES);
}

// Round 6
// 225.381 us; speedup vs baseline: 1.0924x; 1.0924x over previous
//
#include <hip/hip_runtime.h>

#define N_NODES 50000
#define N_EDGES 800000
#define IN_CH 256
#define HID_CH 128
#define OUT_CH 64
#define CAP 64       // bucket slots/node; deg~Poisson(16), P(deg>=64) ~ 1e-18
#define NBINS 196    // ceil(N_NODES/256): bin = dst >> 8
#define PCHUNK 3200
#define PBLOCKS 250  // ceil(N_EDGES/PCHUNK)

typedef _Float16 f16;
typedef _Float16 f16x8 __attribute__((ext_vector_type(8)));
typedef _Float16 f16x2 __attribute__((ext_vector_type(2)));
typedef float f32x4 __attribute__((ext_vector_type(4)));
typedef unsigned short u16;
typedef unsigned int u32;

// ---------------- binned CSR build (4 small kernels) ----------------

// (a) histogram of dst>>8 with LDS pre-aggregation
__global__ __launch_bounds__(256) void k_hist(const int* __restrict__ dst,
                                              int* __restrict__ binCnt, int E) {
    __shared__ int lcnt[NBINS];
    for (int i = threadIdx.x; i < NBINS; i += 256) lcnt[i] = 0;
    __syncthreads();
    int base = blockIdx.x * PCHUNK;
    int end = min(base + PCHUNK, E);
    for (int i = base + (int)threadIdx.x; i < end; i += 256)
        atomicAdd(&lcnt[dst[i] >> 8], 1);
    __syncthreads();
    for (int i = threadIdx.x; i < NBINS; i += 256)
        if (lcnt[i]) atomicAdd(&binCnt[i], lcnt[i]);
}

// (b) exclusive scan of 196 bin counts (single block)
__global__ __launch_bounds__(256) void k_scan(const int* __restrict__ binCnt,
                                              int* __restrict__ binStart,
                                              int* __restrict__ binCursor) {
    __shared__ int s[256];
    int t = threadIdx.x;
    int v = t < NBINS ? binCnt[t] : 0;
    s[t] = v;
    __syncthreads();
    for (int ofs = 1; ofs < 256; ofs <<= 1) {
        int add = (t >= ofs) ? s[t - ofs] : 0;
        __syncthreads();
        s[t] += add;
        __syncthreads();
    }
    int excl = s[t] - v;
    if (t < NBINS) { binStart[t] = excl; binCursor[t] = excl; }
    if (t == 0) binStart[NBINS] = N_EDGES;
}

// (c) place packed codes (dst<<16 | src) into per-bin segments.
// Per-block: LDS-count, one cursor reservation per bin, then write. Writes
// advance 196 contiguous frontiers -> L2 write-combining works.
__global__ __launch_bounds__(256) void k_place(const int* __restrict__ src,
                                               const int* __restrict__ dst,
                                               int* __restrict__ binCursor,
                                               u32* __restrict__ ebuf, int E) {
    __shared__ u32 codes[PCHUNK];
    __shared__ int lcnt[NBINS], lbase[NBINS], lcur[NBINS];
    for (int i = threadIdx.x; i < NBINS; i += 256) lcnt[i] = 0;
    __syncthreads();
    int base = blockIdx.x * PCHUNK;
    int m = min(PCHUNK, E - base);
    for (int j = threadIdx.x; j < m; j += 256) {
        u32 d = (u32)dst[base + j];
        codes[j] = (d << 16) | (u32)src[base + j];
        atomicAdd(&lcnt[d >> 8], 1);
    }
    __syncthreads();
    for (int i = threadIdx.x; i < NBINS; i += 256) {
        lbase[i] = atomicAdd(&binCursor[i], lcnt[i]);
        lcur[i] = 0;
    }
    __syncthreads();
    for (int j = threadIdx.x; j < m; j += 256) {
        u32 c = codes[j];
        int b = c >> 24;
        int p = atomicAdd(&lcur[b], 1);
        ebuf[lbase[b] + p] = c;
    }
}

// (d) one block per bin: build cnt + bucket rows for 256 nodes in LDS,
// write out fully coalesced.
__global__ __launch_bounds__(256) void k_build(const u32* __restrict__ ebuf,
                                               const int* __restrict__ binStart,
                                               int* __restrict__ cnt,
                                               u16* __restrict__ bucket, int N) {
    __shared__ int lcnt[256];
    __shared__ u16 lbuck[256 * CAP];   // 32 KB
    int t = threadIdx.x;
    lcnt[t] = 0;
    __syncthreads();
    int b = blockIdx.x;
    int s = binStart[b], e = binStart[b + 1];
    for (int i = s + t; i < e; i += 256) {
        u32 c = ebuf[i];
        int local = (c >> 16) & 255;
        int p = atomicAdd(&lcnt[local], 1);
        if (p < CAP) lbuck[local * CAP + p] = (u16)(c & 0xFFFFu);
    }
    __syncthreads();
    int nodeBase = b << 8;
    if (nodeBase + t < N) cnt[nodeBase + t] = lcnt[t];
    const uint4* lsrc = (const uint4*)lbuck;
    uint4* gdst = (uint4*)(bucket + (size_t)nodeBase * CAP);
    for (int idx = t; idx < 256 * CAP / 8; idx += 256) {   // 16B chunks, 8/row
        int row = idx >> 3;
        if (nodeBase + row < N) gdst[idx] = lsrc[idx];
    }
}

__global__ __launch_bounds__(256) void k_dis(const int* __restrict__ cnt,
                                             float* __restrict__ dis, int N) {
    int i = blockIdx.x * 256 + threadIdx.x;
    if (i < N) dis[i] = rsqrtf((float)cnt[i] + 1.0f);
}

// ---------------- W -> MFMA B-fragment swizzle (both weights, one kernel) ----------------
template <int K, int N>
__device__ __forceinline__ void swz(const float* __restrict__ W, f16* __restrict__ Bsw,
                                    int idx) {
    constexpr int NTILES = N / 16;
    int j = idx & 7;
    int lane = (idx >> 3) & 63;
    int rest = idx >> 9;
    int nt = rest % NTILES;
    int ks = rest / NTILES;
    int k = ks * 32 + (lane >> 4) * 8 + j;
    int n = nt * 16 + (lane & 15);
    Bsw[idx] = (f16)W[(size_t)k * N + n];
}

__global__ __launch_bounds__(256) void k_swizzle(const float* __restrict__ W1,
                                                 const float* __restrict__ W2,
                                                 f16* __restrict__ B1,
                                                 f16* __restrict__ B2) {
    int idx = blockIdx.x * 256 + threadIdx.x;
    if (idx < IN_CH * HID_CH) {
        swz<IN_CH, HID_CH>(W1, B1, idx);
    } else {
        idx -= IN_CH * HID_CH;
        if (idx < HID_CH * OUT_CH) swz<HID_CH, OUT_CH>(W2, B2, idx);
    }
}

// ---------------- MFMA fp16 GEMM: C = dis[m] * (A@B) ----------------
// 4 waves/block, wave computes 16 rows x N. No LDS/barriers; B pre-swizzled (L2).
template <int K, int N, bool A_FP32, bool RELU>
__global__ __launch_bounds__(256) void k_gemm(const void* __restrict__ Av,
                                              const f16* __restrict__ Bsw,
                                              const float* __restrict__ dis,
                                              f16* __restrict__ C, int M) {
    constexpr int KSTEPS = K / 32, NTILES = N / 16;
    const int tid = threadIdx.x;
    const int wave = tid >> 6, lane = tid & 63;
    const int quad = lane >> 4, l16 = lane & 15;
    int row = blockIdx.x * 64 + wave * 16 + l16;
    const int rowc = row < M ? row : M - 1;

    f32x4 acc[NTILES];
#pragma unroll
    for (int t = 0; t < NTILES; ++t) acc[t] = (f32x4){0.f, 0.f, 0.f, 0.f};

#pragma unroll
    for (int ks = 0; ks < KSTEPS; ++ks) {
        f16x8 afrag;
        if (A_FP32) {
            const float* A = (const float*)Av;
            const float4* p = (const float4*)(A + (size_t)rowc * K + ks * 32 + quad * 8);
            float4 v0 = p[0], v1 = p[1];
            afrag[0] = (f16)v0.x; afrag[1] = (f16)v0.y;
            afrag[2] = (f16)v0.z; afrag[3] = (f16)v0.w;
            afrag[4] = (f16)v1.x; afrag[5] = (f16)v1.y;
            afrag[6] = (f16)v1.z; afrag[7] = (f16)v1.w;
        } else {
            const f16* A = (const f16*)Av;
            afrag = *(const f16x8*)(A + (size_t)rowc * K + ks * 32 + quad * 8);
            if (RELU) {
#pragma unroll
                for (int j = 0; j < 8; ++j)
                    afrag[j] = afrag[j] > (f16)0 ? afrag[j] : (f16)0;
            }
        }
#pragma unroll
        for (int t = 0; t < NTILES; ++t) {
            f16x8 bfrag = *(const f16x8*)(Bsw + (((size_t)ks * NTILES + t) * 64 + lane) * 8);
            acc[t] = __builtin_amdgcn_mfma_f32_16x16x32_f16(afrag, bfrag, acc[t], 0, 0, 0);
        }
    }

    int rbase = blockIdx.x * 64 + wave * 16 + quad * 4;
#pragma unroll
    for (int r = 0; r < 4; ++r) {
        int gr = rbase + r;
        if (gr < M) {
            float d = dis[gr];
#pragma unroll
            for (int t = 0; t < NTILES; ++t)
                C[(size_t)gr * N + t * 16 + l16] = (f16)(acc[t][r] * d);
        }
    }
}

// ---------------- pull: layer-1 half-channel pass (fp16 out) ----------------
// Reads 64 of g1's 128 channels (line-granular) -> per-dispatch gather WS 6.4 MB.
// agg1[u, half*64+c] = du*( g1[u,c'] + sum g1[s,c'] ) + b1[c']
__global__ __launch_bounds__(256) void k_pull_h(const f16* __restrict__ g,
                                                const float* __restrict__ dis,
                                                const float* __restrict__ bias,
                                                const int* __restrict__ cnt,
                                                const u16* __restrict__ bucket,
                                                f16* __restrict__ aggOut, int N,
                                                int half) {
    int tid = blockIdx.x * 256 + threadIdx.x;
    int u = tid >> 5;          // 32 lanes/node, 2 ch/lane
    int sub = tid & 31;
    if (u >= N) return;
    int col = half * 64 + sub * 2;
    const f16* gp = g + col;

    f16x2 hv = *(const f16x2*)(gp + (size_t)u * HID_CH);
    float a0 = (float)hv[0], a1 = (float)hv[1];

    int n = cnt[u];
    if (n > CAP) n = CAP;
    const u16* row = bucket + u * CAP;

    int k = 0;
    for (; k + 4 <= n; k += 4) {
        ushort4 s4 = *(const ushort4*)(row + k);
        f16x2 v0 = *(const f16x2*)(gp + (size_t)s4.x * HID_CH);
        f16x2 v1 = *(const f16x2*)(gp + (size_t)s4.y * HID_CH);
        f16x2 v2 = *(const f16x2*)(gp + (size_t)s4.z * HID_CH);
        f16x2 v3 = *(const f16x2*)(gp + (size_t)s4.w * HID_CH);
        a0 += (float)v0[0] + (float)v1[0] + (float)v2[0] + (float)v3[0];
        a1 += (float)v0[1] + (float)v1[1] + (float)v2[1] + (float)v3[1];
    }
    for (; k < n; ++k) {
        f16x2 v = *(const f16x2*)(gp + (size_t)row[k] * HID_CH);
        a0 += (float)v[0];
        a1 += (float)v[1];
    }

    float du = dis[u];
    f16x2 o;
    o[0] = (f16)fmaf(du, a0, bias[col]);
    o[1] = (f16)fmaf(du, a1, bias[col + 1]);
    *(f16x2*)(aggOut + (size_t)u * HID_CH + col) = o;
}

// ---------------- pull: layer-2 (fused ReLU, fp32 out) ----------------
__global__ __launch_bounds__(256) void k_pull_out(const f16* __restrict__ g,
                                                  const float* __restrict__ dis,
                                                  const float* __restrict__ bias,
                                                  const int* __restrict__ cnt,
                                                  const u16* __restrict__ bucket,
                                                  float2* __restrict__ out, int N) {
    int tid = blockIdx.x * 256 + threadIdx.x;
    int u = tid >> 5;          // 32 lanes/node, 2 ch/lane
    int sub = tid & 31;
    if (u >= N) return;
    const f16* gp = g + sub * 2;

    f16x2 hv = *(const f16x2*)(gp + (size_t)u * OUT_CH);
    float a0 = (float)hv[0], a1 = (float)hv[1];

    int n = cnt[u];
    if (n > CAP) n = CAP;
    const u16* row = bucket + u * CAP;

    int k = 0;
    for (; k + 4 <= n; k += 4) {
        ushort4 s4 = *(const ushort4*)(row + k);
        f16x2 v0 = *(const f16x2*)(gp + (size_t)s4.x * OUT_CH);
        f16x2 v1 = *(const f16x2*)(gp + (size_t)s4.y * OUT_CH);
        f16x2 v2 = *(const f16x2*)(gp + (size_t)s4.z * OUT_CH);
        f16x2 v3 = *(const f16x2*)(gp + (size_t)s4.w * OUT_CH);
        a0 += (float)v0[0] + (float)v1[0] + (float)v2[0] + (float)v3[0];
        a1 += (float)v0[1] + (float)v1[1] + (float)v2[1] + (float)v3[1];
    }
    for (; k < n; ++k) {
        f16x2 v = *(const f16x2*)(gp + (size_t)row[k] * OUT_CH);
        a0 += (float)v[0];
        a1 += (float)v[1];
    }

    float du = dis[u];
    float o0 = fmaf(du, a0, bias[sub * 2]);
    float o1 = fmaf(du, a1, bias[sub * 2 + 1]);
    out[(size_t)u * 32 + sub] = make_float2(fmaxf(o0, 0.f), fmaxf(o1, 0.f));
}

// ---------------- launch ----------------

extern "C" void kernel_launch(void* const* d_in, const int* in_sizes, int n_in,
                              void* d_out, int out_size, void* d_ws, size_t ws_size,
                              hipStream_t stream) {
    const float* x  = (const float*)d_in[0];
    const int* ei   = (const int*)d_in[1];
    const float* W1 = (const float*)d_in[2];
    const float* b1 = (const float*)d_in[3];
    const float* W2 = (const float*)d_in[4];
    const float* b2 = (const float*)d_in[5];
    float* out = (float*)d_out;

    const int* src = ei;
    const int* dst = ei + N_EDGES;

    char* ws = (char*)d_ws;
    size_t off = 0;
    auto alloc = [&](size_t bytes) -> void* {
        off = (off + 255) & ~(size_t)255;
        void* p = ws + off;
        off += bytes;
        return p;
    };
    int*   binCnt    = (int*)alloc((size_t)NBINS * 4);
    int*   binStart  = (int*)alloc((size_t)(NBINS + 1) * 4);
    int*   binCursor = (int*)alloc((size_t)NBINS * 4);
    u32*   ebuf      = (u32*)alloc((size_t)N_EDGES * 4);            // 3.2 MB
    int*   cnt       = (int*)alloc((size_t)N_NODES * 4);
    float* dis       = (float*)alloc((size_t)N_NODES * 4);
    u16*   bucket    = (u16*)alloc((size_t)N_NODES * CAP * 2);      // 6.4 MB
    f16*   W1sw      = (f16*)alloc((size_t)IN_CH * HID_CH * 2);
    f16*   W2sw      = (f16*)alloc((size_t)HID_CH * OUT_CH * 2);
    f16*   g1        = (f16*)alloc((size_t)N_NODES * HID_CH * 2);   // 12.8 MB, prescaled
    f16*   agg1      = (f16*)alloc((size_t)N_NODES * HID_CH * 2);   // 12.8 MB
    f16*   g2        = (f16*)alloc((size_t)N_NODES * OUT_CH * 2);   // 6.4 MB, prescaled

    hipMemsetAsync(binCnt, 0, (size_t)NBINS * 4, stream);
    k_swizzle<<<(IN_CH * HID_CH + HID_CH * OUT_CH + 255) / 256, 256, 0, stream>>>(
        W1, W2, W1sw, W2sw);

    // binned counting-sort CSR build
    k_hist<<<PBLOCKS, 256, 0, stream>>>(dst, binCnt, N_EDGES);
    k_scan<<<1, 256, 0, stream>>>(binCnt, binStart, binCursor);
    k_place<<<PBLOCKS, 256, 0, stream>>>(src, dst, binCursor, ebuf, N_EDGES);
    k_build<<<NBINS, 256, 0, stream>>>(ebuf, binStart, cnt, bucket, N_NODES);
    k_dis<<<(N_NODES + 255) / 256, 256, 0, stream>>>(cnt, dis, N_NODES);

    // layer 1: g1 = dis*(x @ W1); agg1 = du*(g1[u]+sum g1[s]) + b1  (pre-ReLU)
    k_gemm<IN_CH, HID_CH, true, false><<<(N_NODES + 63) / 64, 256, 0, stream>>>(
        x, W1sw, dis, g1, N_NODES);
    const int pullBlocks = (N_NODES * 32 + 255) / 256;
    k_pull_h<<<pullBlocks, 256, 0, stream>>>(g1, dis, b1, cnt, bucket, agg1, N_NODES, 0);
    k_pull_h<<<pullBlocks, 256, 0, stream>>>(g1, dis, b1, cnt, bucket, agg1, N_NODES, 1);

    // layer 2: g2 = dis*(relu(agg1) @ W2); out = relu(du*(g2[u]+sum g2[s]) + b2)
    k_gemm<HID_CH, OUT_CH, false, true><<<(N_NODES + 63) / 64, 256, 0, stream>>>(
        agg1, W2sw, dis, g2, N_NODES);
    k_pull_out<<<pullBlocks, 256, 0, stream>>>(g2, dis, b2, cnt, bucket,
                                               (float2*)out, N_NODES);
}

// Round 7
// 200.827 us; speedup vs baseline: 1.2259x; 1.1223x over previous
//
#include <hip/hip_runtime.h>

#define N_NODES 50000
#define N_EDGES 800000
#define IN_CH 256
#define HID_CH 128
#define OUT_CH 64
#define CAP 64       // bucket slots/node; deg~Poisson(16), P(deg>=64) ~ 1e-18
#define NBINS 196    // ceil(N_NODES/256): bin = dst >> 8
#define PCHUNK 3200
#define PBLOCKS 250  // ceil(N_EDGES/PCHUNK)
#define SWZ_BLOCKS ((IN_CH * HID_CH + HID_CH * OUT_CH) / 256)   // 160

typedef _Float16 f16;
typedef _Float16 f16x8 __attribute__((ext_vector_type(8)));
typedef _Float16 f16x2 __attribute__((ext_vector_type(2)));
typedef float f32x4 __attribute__((ext_vector_type(4)));
typedef unsigned short u16;
typedef unsigned int u32;

// ---------------- W -> MFMA B-fragment swizzle (device body) ----------------
template <int K, int N>
__device__ __forceinline__ void swz(const float* __restrict__ W, f16* __restrict__ Bsw,
                                    int idx) {
    constexpr int NTILES = N / 16;
    int j = idx & 7;
    int lane = (idx >> 3) & 63;
    int rest = idx >> 9;
    int nt = rest % NTILES;
    int ks = rest / NTILES;
    int k = ks * 32 + (lane >> 4) * 8 + j;
    int n = nt * 16 + (lane & 15);
    Bsw[idx] = (f16)W[(size_t)k * N + n];
}

// ---------------- fused: dst-bin histogram + weight swizzle ----------------
// Blocks [0, PBLOCKS): histogram of dst>>8 (LDS pre-agg).
// Blocks [PBLOCKS, PBLOCKS+SWZ_BLOCKS): swizzle W1/W2 to MFMA fragment order.
__global__ __launch_bounds__(256) void k_pre(const int* __restrict__ dst,
                                             int* __restrict__ binCnt, int E,
                                             const float* __restrict__ W1,
                                             const float* __restrict__ W2,
                                             f16* __restrict__ B1,
                                             f16* __restrict__ B2) {
    if ((int)blockIdx.x < PBLOCKS) {
        __shared__ int lcnt[NBINS];
        for (int i = threadIdx.x; i < NBINS; i += 256) lcnt[i] = 0;
        __syncthreads();
        int base = blockIdx.x * PCHUNK;
        int end = min(base + PCHUNK, E);
        for (int i = base + (int)threadIdx.x; i < end; i += 256)
            atomicAdd(&lcnt[dst[i] >> 8], 1);
        __syncthreads();
        for (int i = threadIdx.x; i < NBINS; i += 256)
            if (lcnt[i]) atomicAdd(&binCnt[i], lcnt[i]);
        return;
    }
    int idx = ((int)blockIdx.x - PBLOCKS) * 256 + threadIdx.x;
    if (idx < IN_CH * HID_CH) {
        swz<IN_CH, HID_CH>(W1, B1, idx);
    } else {
        idx -= IN_CH * HID_CH;
        if (idx < HID_CH * OUT_CH) swz<HID_CH, OUT_CH>(W2, B2, idx);
    }
}

// ---------------- exclusive scan of bin counts (single block) ----------------
__global__ __launch_bounds__(256) void k_scan(const int* __restrict__ binCnt,
                                              int* __restrict__ binStart,
                                              int* __restrict__ binCursor) {
    __shared__ int s[256];
    int t = threadIdx.x;
    int v = t < NBINS ? binCnt[t] : 0;
    s[t] = v;
    __syncthreads();
    for (int ofs = 1; ofs < 256; ofs <<= 1) {
        int add = (t >= ofs) ? s[t - ofs] : 0;
        __syncthreads();
        s[t] += add;
        __syncthreads();
    }
    int excl = s[t] - v;
    if (t < NBINS) { binStart[t] = excl; binCursor[t] = excl; }
    if (t == 0) binStart[NBINS] = N_EDGES;
}

// ---------------- place packed (dst<<16|src) codes into bin segments ----------------
__global__ __launch_bounds__(256) void k_place(const int* __restrict__ src,
                                               const int* __restrict__ dst,
                                               int* __restrict__ binCursor,
                                               u32* __restrict__ ebuf, int E) {
    __shared__ u32 codes[PCHUNK];
    __shared__ int lcnt[NBINS], lbase[NBINS], lcur[NBINS];
    for (int i = threadIdx.x; i < NBINS; i += 256) lcnt[i] = 0;
    __syncthreads();
    int base = blockIdx.x * PCHUNK;
    int m = min(PCHUNK, E - base);
    for (int j = threadIdx.x; j < m; j += 256) {
        u32 d = (u32)dst[base + j];
        codes[j] = (d << 16) | (u32)src[base + j];
        atomicAdd(&lcnt[d >> 8], 1);
    }
    __syncthreads();
    for (int i = threadIdx.x; i < NBINS; i += 256) {
        lbase[i] = atomicAdd(&binCursor[i], lcnt[i]);
        lcur[i] = 0;
    }
    __syncthreads();
    for (int j = threadIdx.x; j < m; j += 256) {
        u32 c = codes[j];
        int b = c >> 24;
        int p = atomicAdd(&lcur[b], 1);
        ebuf[lbase[b] + p] = c;
    }
}

// ---------------- per-bin CSR build in LDS + cnt + dis (fused) ----------------
__global__ __launch_bounds__(256) void k_build(const u32* __restrict__ ebuf,
                                               const int* __restrict__ binStart,
                                               int* __restrict__ cnt,
                                               float* __restrict__ dis,
                                               u16* __restrict__ bucket, int N) {
    __shared__ int lcnt[256];
    __shared__ u16 lbuck[256 * CAP];   // 32 KB
    int t = threadIdx.x;
    lcnt[t] = 0;
    __syncthreads();
    int b = blockIdx.x;
    int s = binStart[b], e = binStart[b + 1];
    for (int i = s + t; i < e; i += 256) {
        u32 c = ebuf[i];
        int local = (c >> 16) & 255;
        int p = atomicAdd(&lcnt[local], 1);
        if (p < CAP) lbuck[local * CAP + p] = (u16)(c & 0xFFFFu);
    }
    __syncthreads();
    int nodeBase = b << 8;
    if (nodeBase + t < N) {
        cnt[nodeBase + t] = lcnt[t];
        dis[nodeBase + t] = rsqrtf((float)lcnt[t] + 1.0f);
    }
    const uint4* lsrc = (const uint4*)lbuck;
    uint4* gdst = (uint4*)(bucket + (size_t)nodeBase * CAP);
    for (int idx = t; idx < 256 * CAP / 8; idx += 256) {   // 16B chunks, 8/row
        int row = idx >> 3;
        if (nodeBase + row < N) gdst[idx] = lsrc[idx];
    }
}

// ---------------- MFMA fp16 GEMM: C = dis[m] * (A@B) ----------------
// 4 waves/block, wave computes 16 rows x N. No LDS/barriers; B pre-swizzled (L2).
template <int K, int N, bool A_FP32, bool RELU>
__global__ __launch_bounds__(256) void k_gemm(const void* __restrict__ Av,
                                              const f16* __restrict__ Bsw,
                                              const float* __restrict__ dis,
                                              f16* __restrict__ C, int M) {
    constexpr int KSTEPS = K / 32, NTILES = N / 16;
    const int tid = threadIdx.x;
    const int wave = tid >> 6, lane = tid & 63;
    const int quad = lane >> 4, l16 = lane & 15;
    int row = blockIdx.x * 64 + wave * 16 + l16;
    const int rowc = row < M ? row : M - 1;

    f32x4 acc[NTILES];
#pragma unroll
    for (int t = 0; t < NTILES; ++t) acc[t] = (f32x4){0.f, 0.f, 0.f, 0.f};

#pragma unroll
    for (int ks = 0; ks < KSTEPS; ++ks) {
        f16x8 afrag;
        if (A_FP32) {
            const float* A = (const float*)Av;
            const float4* p = (const float4*)(A + (size_t)rowc * K + ks * 32 + quad * 8);
            float4 v0 = p[0], v1 = p[1];
            afrag[0] = (f16)v0.x; afrag[1] = (f16)v0.y;
            afrag[2] = (f16)v0.z; afrag[3] = (f16)v0.w;
            afrag[4] = (f16)v1.x; afrag[5] = (f16)v1.y;
            afrag[6] = (f16)v1.z; afrag[7] = (f16)v1.w;
        } else {
            const f16* A = (const f16*)Av;
            afrag = *(const f16x8*)(A + (size_t)rowc * K + ks * 32 + quad * 8);
            if (RELU) {
#pragma unroll
                for (int j = 0; j < 8; ++j)
                    afrag[j] = afrag[j] > (f16)0 ? afrag[j] : (f16)0;
            }
        }
#pragma unroll
        for (int t = 0; t < NTILES; ++t) {
            f16x8 bfrag = *(const f16x8*)(Bsw + (((size_t)ks * NTILES + t) * 64 + lane) * 8);
            acc[t] = __builtin_amdgcn_mfma_f32_16x16x32_f16(afrag, bfrag, acc[t], 0, 0, 0);
        }
    }

    int rbase = blockIdx.x * 64 + wave * 16 + quad * 4;
#pragma unroll
    for (int r = 0; r < 4; ++r) {
        int gr = rbase + r;
        if (gr < M) {
            float d = dis[gr];
#pragma unroll
            for (int t = 0; t < NTILES; ++t)
                C[(size_t)gr * N + t * 16 + l16] = (f16)(acc[t][r] * d);
        }
    }
}

// ---------------- pull aggregation: pure gather-sum, unroll 8 ----------------
// LPN lanes per node, 2 ch/lane. g pre-scaled (g = dis*h).
// fp16 out (pre-ReLU agg1) or fused-ReLU fp32 out (final).
template <int C, bool RELU_OUT_F32>
__global__ __launch_bounds__(256) void k_pull(const f16* __restrict__ g,
                                              const float* __restrict__ dis,
                                              const float* __restrict__ bias,
                                              const int* __restrict__ cnt,
                                              const u16* __restrict__ bucket,
                                              void* __restrict__ outv, int N) {
    constexpr int LPN = C / 2;
    int tid = blockIdx.x * 256 + threadIdx.x;
    int u = tid / LPN;
    int sub = tid % LPN;
    if (u >= N) return;
    const f16* gp = g + sub * 2;

    f16x2 hv = *(const f16x2*)(gp + (size_t)u * C);
    float a0 = (float)hv[0], a1 = (float)hv[1];

    int n = cnt[u];
    if (n > CAP) n = CAP;
    const u16* row = bucket + u * CAP;   // 128B-aligned rows

    int k = 0;
    for (; k + 8 <= n; k += 8) {
        uint4 iv = *(const uint4*)(row + k);           // 8 indices, one 16B load
        int s0 = iv.x & 0xFFFF, s1 = iv.x >> 16;
        int s2 = iv.y & 0xFFFF, s3 = iv.y >> 16;
        int s4 = iv.z & 0xFFFF, s5 = iv.z >> 16;
        int s6 = iv.w & 0xFFFF, s7 = iv.w >> 16;
        f16x2 v0 = *(const f16x2*)(gp + (size_t)s0 * C);
        f16x2 v1 = *(const f16x2*)(gp + (size_t)s1 * C);
        f16x2 v2 = *(const f16x2*)(gp + (size_t)s2 * C);
        f16x2 v3 = *(const f16x2*)(gp + (size_t)s3 * C);
        f16x2 v4 = *(const f16x2*)(gp + (size_t)s4 * C);
        f16x2 v5 = *(const f16x2*)(gp + (size_t)s5 * C);
        f16x2 v6 = *(const f16x2*)(gp + (size_t)s6 * C);
        f16x2 v7 = *(const f16x2*)(gp + (size_t)s7 * C);
        a0 += ((float)v0[0] + (float)v1[0]) + ((float)v2[0] + (float)v3[0]) +
              (((float)v4[0] + (float)v5[0]) + ((float)v6[0] + (float)v7[0]));
        a1 += ((float)v0[1] + (float)v1[1]) + ((float)v2[1] + (float)v3[1]) +
              (((float)v4[1] + (float)v5[1]) + ((float)v6[1] + (float)v7[1]));
    }
    if (k + 4 <= n) {
        ushort4 s4v = *(const ushort4*)(row + k);
        f16x2 v0 = *(const f16x2*)(gp + (size_t)s4v.x * C);
        f16x2 v1 = *(const f16x2*)(gp + (size_t)s4v.y * C);
        f16x2 v2 = *(const f16x2*)(gp + (size_t)s4v.z * C);
        f16x2 v3 = *(const f16x2*)(gp + (size_t)s4v.w * C);
        a0 += ((float)v0[0] + (float)v1[0]) + ((float)v2[0] + (float)v3[0]);
        a1 += ((float)v0[1] + (float)v1[1]) + ((float)v2[1] + (float)v3[1]);
        k += 4;
    }
    for (; k < n; ++k) {
        f16x2 v = *(const f16x2*)(gp + (size_t)row[k] * C);
        a0 += (float)v[0];
        a1 += (float)v[1];
    }

    float du = dis[u];
    float o0 = fmaf(du, a0, bias[sub * 2]);
    float o1 = fmaf(du, a1, bias[sub * 2 + 1]);
    if (RELU_OUT_F32) {
        float2* out = (float2*)outv;
        out[(size_t)u * LPN + sub] = make_float2(fmaxf(o0, 0.f), fmaxf(o1, 0.f));
    } else {
        f16x2 o;
        o[0] = (f16)o0; o[1] = (f16)o1;
        *(f16x2*)((f16*)outv + (size_t)u * C + sub * 2) = o;
    }
}

// ---------------- launch ----------------

extern "C" void kernel_launch(void* const* d_in, const int* in_sizes, int n_in,
                              void* d_out, int out_size, void* d_ws, size_t ws_size,
                              hipStream_t stream) {
    const float* x  = (const float*)d_in[0];
    const int* ei   = (const int*)d_in[1];
    const float* W1 = (const float*)d_in[2];
    const float* b1 = (const float*)d_in[3];
    const float* W2 = (const float*)d_in[4];
    const float* b2 = (const float*)d_in[5];
    float* out = (float*)d_out;

    const int* src = ei;
    const int* dst = ei + N_EDGES;

    char* ws = (char*)d_ws;
    size_t off = 0;
    auto alloc = [&](size_t bytes) -> void* {
        off = (off + 255) & ~(size_t)255;
        void* p = ws + off;
        off += bytes;
        return p;
    };
    int*   binCnt    = (int*)alloc((size_t)NBINS * 4);
    int*   binStart  = (int*)alloc((size_t)(NBINS + 1) * 4);
    int*   binCursor = (int*)alloc((size_t)NBINS * 4);
    u32*   ebuf      = (u32*)alloc((size_t)N_EDGES * 4);            // 3.2 MB
    int*   cnt       = (int*)alloc((size_t)N_NODES * 4);
    float* dis       = (float*)alloc((size_t)N_NODES * 4);
    u16*   bucket    = (u16*)alloc((size_t)N_NODES * CAP * 2);      // 6.4 MB
    f16*   W1sw      = (f16*)alloc((size_t)IN_CH * HID_CH * 2);
    f16*   W2sw      = (f16*)alloc((size_t)HID_CH * OUT_CH * 2);
    f16*   g1        = (f16*)alloc((size_t)N_NODES * HID_CH * 2);   // 12.8 MB, prescaled
    f16*   agg1      = (f16*)alloc((size_t)N_NODES * HID_CH * 2);   // 12.8 MB
    f16*   g2        = (f16*)alloc((size_t)N_NODES * OUT_CH * 2);   // 6.4 MB, prescaled

    hipMemsetAsync(binCnt, 0, (size_t)NBINS * 4, stream);

    // fused histogram + weight swizzle
    k_pre<<<PBLOCKS + SWZ_BLOCKS, 256, 0, stream>>>(dst, binCnt, N_EDGES,
                                                    W1, W2, W1sw, W2sw);
    k_scan<<<1, 256, 0, stream>>>(binCnt, binStart, binCursor);
    k_place<<<PBLOCKS, 256, 0, stream>>>(src, dst, binCursor, ebuf, N_EDGES);
    k_build<<<NBINS, 256, 0, stream>>>(ebuf, binStart, cnt, dis, bucket, N_NODES);

    // layer 1: g1 = dis*(x @ W1); agg1 = du*(g1[u]+sum g1[s]) + b1  (pre-ReLU)
    k_gemm<IN_CH, HID_CH, true, false><<<(N_NODES + 63) / 64, 256, 0, stream>>>(
        x, W1sw, dis, g1, N_NODES);
    k_pull<HID_CH, false><<<(N_NODES * (HID_CH / 2) + 255) / 256, 256, 0, stream>>>(
        g1, dis, b1, cnt, bucket, agg1, N_NODES);

    // layer 2: g2 = dis*(relu(agg1) @ W2); out = relu(du*(g2[u]+sum g2[s]) + b2)
    k_gemm<HID_CH, OUT_CH, false, true><<<(N_NODES + 63) / 64, 256, 0, stream>>>(
        agg1, W2sw, dis, g2, N_NODES);
    k_pull<OUT_CH, true><<<(N_NODES * (OUT_CH / 2) + 255) / 256, 256, 0, stream>>>(
        g2, dis, b2, cnt, bucket, out, N_NODES);
}